// Round 10
// baseline (96.221 us; speedup 1.0000x reference)
//
#include <hip/hip_runtime.h>

// Per-edge dot product: out[e] = dot(user_h[src[e]], game_h[dst[e]]), D=128.
//
// Prep (memsetAsync + 1 fused kernel):
//   [scatter blocks] bucket edges by SRC block into NB=64 buckets. Records are
//     4 B: rel_src:11 | dst:16. LDS-staged, flushed as coalesced runs.
//     pos[e] = global slot for the final out pass.
//   [convert blocks] BOTH tables f32 -> bf16 (row = 16 uint4).
// Main: bucket b on XCD slot b%8 (bid&7 round-robin), 8 buckets sequential
//   per XCD -> 400 KB bf16 user slice L2-resident; game bf16 random gather.
//   BPB=98: each block runs ~8 iterations (amortizes cursor/setup); record
//   pairs prefetched one iteration ahead; dot uses float2 packed FMA
//   (v_pk_fma_f32). Results written SEQUENTIALLY to res.
// Final: out[e] = res[pos[e]] — pos has block-level locality.
// Fallback: direct f32 kernel if shape guards fail.

#define DIM 128
#define NB 64
#define CAP 28160        // per-bucket capacity (mean E/64, +many sigma)
#define BPB 98           // main-kernel chunks per bucket (~8 iters/block)
#define EPB_A 4096
#define LCAP 128         // LDS staging slots per bucket per block

typedef float f32x2 __attribute__((ext_vector_type(2)));

__device__ inline unsigned bf16rn(float f) {
    unsigned x = __float_as_uint(f);
    return (x + 0x7FFFu + ((x >> 16) & 1u)) >> 16;
}

// Fused prep: blocks [0,nscat) scatter; [nscat,nscat+nublk) convert user;
// [nscat+nublk, nscat+nublk+ngblk) convert game.
__global__ void __launch_bounds__(256) prep_fused(
    const float* __restrict__ user_h, const float* __restrict__ game_h,
    const int* __restrict__ src_idx, const int* __restrict__ dst_idx, int E,
    unsigned n_users,
    unsigned* __restrict__ cursors, unsigned* __restrict__ records,
    unsigned* __restrict__ pos,
    uint4* __restrict__ user_bf, uint4* __restrict__ game_bf,
    int nscat, int nublk, int nu8, int ng8)
{
    __shared__ unsigned hist[NB];
    __shared__ unsigned base_s[NB];
    __shared__ unsigned lcur[NB];
    __shared__ unsigned stage[NB][LCAP];   // 32 KB
    int bid = blockIdx.x;
    int tid = threadIdx.x;

    if (bid >= nscat) {
        // ---- convert branch (straight element order) ----
        const float* in;
        uint4* outp;
        int i, n8;
        if (bid < nscat + nublk) {
            i = (bid - nscat) * 256 + tid;  n8 = nu8;  in = user_h;  outp = user_bf;
        } else {
            i = (bid - nscat - nublk) * 256 + tid;  n8 = ng8;  in = game_h;  outp = game_bf;
        }
        if (i < n8) {
            const float4* in4 = (const float4*)in;
            float4 a = in4[2 * i];
            float4 b = in4[2 * i + 1];
            uint4 o;
            o.x = bf16rn(a.x) | (bf16rn(a.y) << 16);
            o.y = bf16rn(a.z) | (bf16rn(a.w) << 16);
            o.z = bf16rn(b.x) | (bf16rn(b.y) << 16);
            o.w = bf16rn(b.z) | (bf16rn(b.w) << 16);
            outp[i] = o;
        }
        return;
    }

    // ---- scatter branch: bucket by SRC block, single idx read ----
    long long start = (long long)bid * EPB_A;
    unsigned ss[16], dd[16];

    #pragma unroll
    for (int k = 0; k < 16; ++k) {
        long long e = start + k * 256 + tid;
        bool v = (e < E);
        ss[k] = v ? (unsigned)src_idx[e] : 0xFFFFFFFFu;   // sentinel = invalid
        dd[k] = v ? (unsigned)dst_idx[e] : 0u;
    }

    if (tid < NB) hist[tid] = 0u;
    __syncthreads();

    #pragma unroll
    for (int k = 0; k < 16; ++k) {
        if (ss[k] != 0xFFFFFFFFu) {
            unsigned b = (ss[k] * (unsigned)NB) / n_users;
            atomicAdd(&hist[b], 1u);
        }
    }
    __syncthreads();

    if (tid < NB) {
        base_s[tid] = atomicAdd(&cursors[tid * 32], hist[tid]);  // prior count
        lcur[tid] = 0u;
    }
    __syncthreads();

    #pragma unroll
    for (int k = 0; k < 16; ++k) {
        if (ss[k] != 0xFFFFFFFFu) {
            unsigned s = ss[k], d = dd[k];
            unsigned b = (s * (unsigned)NB) / n_users;
            unsigned sbase = (b * n_users + (unsigned)NB - 1u) / (unsigned)NB;
            unsigned rec = (s - sbase) | (d << 11);    // rel_src:11 | dst:16
            unsigned r = atomicAdd(&lcur[b], 1u);
            unsigned slot = base_s[b] + r;
            long long e = start + k * 256 + tid;
            if (slot < (unsigned)CAP) {
                pos[e] = b * (unsigned)CAP + slot;
                if (r < (unsigned)LCAP) stage[b][r] = rec;          // common
                else records[(size_t)b * CAP + slot] = rec;          // rare
            } else {
                pos[e] = 0xFFFFFFFFu;                                // never
            }
        }
    }
    __syncthreads();

    // ---- coalesced flush: one wave per bucket, contiguous runs ----
    int wid  = tid >> 6;     // 0..3
    int lane = tid & 63;
    for (int b = wid; b < NB; b += 4) {
        unsigned n  = lcur[b]; if (n > (unsigned)LCAP) n = (unsigned)LCAP;
        unsigned bs = base_s[b];
        unsigned lim = (bs < (unsigned)CAP) ? ((unsigned)CAP - bs) : 0u;
        if (n > lim) n = lim;
        unsigned gbase = (unsigned)b * (unsigned)CAP + bs;
        for (unsigned i = lane; i < n; i += 64)
            records[gbase + i] = stage[b][i];
    }
}

// unpack one uint (2 bf16) into a float2 {lo, hi}
__device__ inline f32x2 bf2_unpack(unsigned u) {
    uint2 w;
    w.x = u << 16;
    w.y = u & 0xFFFF0000u;
    return *(f32x2*)&w;
}

// dot of 8 bf16 pairs via packed f32 FMA (v_pk_fma_f32)
__device__ inline float dot8_bf16(uint4 a, uint4 b) {
    f32x2 acc = bf2_unpack(a.x) * bf2_unpack(b.x);
    acc = bf2_unpack(a.y) * bf2_unpack(b.y) + acc;
    acc = bf2_unpack(a.z) * bf2_unpack(b.z) + acc;
    acc = bf2_unpack(a.w) * bf2_unpack(b.w) + acc;
    return acc.x + acc.y;
}

__global__ void __launch_bounds__(256) edge_dot_bucketed_bf16(
    const uint4* __restrict__ user_bf, const uint4* __restrict__ game_bf,
    const unsigned* __restrict__ cursors, const unsigned* __restrict__ records,
    unsigned n_users, float* __restrict__ res)
{
    int bid = blockIdx.x;
    int x = bid & 7;          // XCD slot (round-robin dispatch heuristic)
    int n = bid >> 3;
    int bq = n / BPB;         // which of this XCD's 8 buckets
    int chunk = n - bq * BPB;
    int b = x + 8 * bq;

    int count = (int)cursors[b * 32];
    if (count > CAP) count = CAP;
    const unsigned* __restrict__ rec = records + (size_t)b * CAP;
    float* __restrict__ rout = res + (size_t)b * CAP;
    unsigned sbase = ((unsigned)b * n_users + (unsigned)NB - 1u) / (unsigned)NB;

    int g    = threadIdx.x >> 4;   // 16-lane group (0..15)
    int lane = threadIdx.x & 15;

    int j = chunk * 32 + 2 * g;
    if (j >= count) return;

    uint2 rr = *(const uint2*)(rec + j);   // j even; CAP even so j+1 in range

    while (true) {
        int jn = j + BPB * 32;
        uint2 rrn;
        bool more = (jn < count);
        if (more) rrn = *(const uint2*)(rec + jn);   // prefetch next iteration

        bool has1 = (j + 1 < count);
        unsigned r0 = rr.x;
        unsigned r1 = has1 ? rr.y : rr.x;

        unsigned s0 = sbase + (r0 & 0x7FFu);
        unsigned d0 = r0 >> 11;
        unsigned s1 = sbase + (r1 & 0x7FFu);
        unsigned d1 = r1 >> 11;

        // lane owns elements [8*lane, 8*lane+8): 1 uint4 per row per table
        uint4 ua = user_bf[(size_t)s0 * 16 + lane];
        uint4 va = game_bf[(size_t)d0 * 16 + lane];
        uint4 ub = user_bf[(size_t)s1 * 16 + lane];
        uint4 vb = game_bf[(size_t)d1 * 16 + lane];

        float sum0 = dot8_bf16(ua, va);
        float sum1 = dot8_bf16(ub, vb);

        sum0 += __shfl_xor(sum0, 1);  sum1 += __shfl_xor(sum1, 1);
        sum0 += __shfl_xor(sum0, 2);  sum1 += __shfl_xor(sum1, 2);
        sum0 += __shfl_xor(sum0, 4);  sum1 += __shfl_xor(sum1, 4);
        sum0 += __shfl_xor(sum0, 8);  sum1 += __shfl_xor(sum1, 8);

        if (lane == 0) {
            if (has1) {
                *(float2*)(rout + j) = make_float2(sum0, sum1);  // j even
            } else {
                rout[j] = sum0;
            }
        }

        if (!more) break;
        j = jn;
        rr = rrn;
    }
}

// Final: out[e] = res[pos[e]], vectorized x4; pos permutation is block-local.
__global__ void __launch_bounds__(256) scatter_out(
    const unsigned* __restrict__ pos, const float* __restrict__ res,
    float* __restrict__ out, int E)
{
    int i4 = blockIdx.x * blockDim.x + threadIdx.x;
    int n4 = E >> 2;
    if (i4 < n4) {
        uint4 p = ((const uint4*)pos)[i4];
        float4 o;
        o.x = (p.x != 0xFFFFFFFFu) ? res[p.x] : 0.0f;
        o.y = (p.y != 0xFFFFFFFFu) ? res[p.y] : 0.0f;
        o.z = (p.z != 0xFFFFFFFFu) ? res[p.z] : 0.0f;
        o.w = (p.w != 0xFFFFFFFFu) ? res[p.w] : 0.0f;
        ((float4*)out)[i4] = o;
    } else if (i4 == n4) {
        for (int e = n4 * 4; e < E; ++e) {
            unsigned p = pos[e];
            out[e] = (p != 0xFFFFFFFFu) ? res[p] : 0.0f;
        }
    }
}

// ---------------- direct fallback (all f32) ----------------
__global__ void __launch_bounds__(256) edge_dot_kernel(
    const float* __restrict__ user_h,
    const float* __restrict__ game_h,
    const int* __restrict__ src_idx,
    const int* __restrict__ dst_idx,
    float* __restrict__ out,
    int E)
{
    int tid  = blockIdx.x * blockDim.x + threadIdx.x;
    int g    = tid >> 4;
    int lane = tid & 15;
    long long e0 = (long long)g * 2;
    if (e0 >= E) return;
    bool has1 = (e0 + 1 < E);

    int s0 = src_idx[e0];
    int d0 = dst_idx[e0];
    int s1 = has1 ? src_idx[e0 + 1] : s0;
    int d1 = has1 ? dst_idx[e0 + 1] : d0;

    const float4* __restrict__ u0 = (const float4*)(user_h + (size_t)s0 * DIM);
    const float4* __restrict__ v0 = (const float4*)(game_h + (size_t)d0 * DIM);
    const float4* __restrict__ u1 = (const float4*)(user_h + (size_t)s1 * DIM);
    const float4* __restrict__ v1 = (const float4*)(game_h + (size_t)d1 * DIM);

    float4 ua0 = u0[lane];
    float4 ua1 = u0[lane + 16];
    float4 va0 = v0[lane];
    float4 va1 = v0[lane + 16];
    float4 ub0 = u1[lane];
    float4 ub1 = u1[lane + 16];
    float4 vb0 = v1[lane];
    float4 vb1 = v1[lane + 16];

    float sum0 = ua0.x * va0.x + ua0.y * va0.y + ua0.z * va0.z + ua0.w * va0.w
               + ua1.x * va1.x + ua1.y * va1.y + ua1.z * va1.z + ua1.w * va1.w;
    float sum1 = ub0.x * vb0.x + ub0.y * vb0.y + ub0.z * vb0.z + ub0.w * vb0.w
               + ub1.x * vb1.x + ub1.y * vb1.y + ub1.z * vb1.z + ub1.w * vb1.w;

    sum0 += __shfl_xor(sum0, 1);  sum1 += __shfl_xor(sum1, 1);
    sum0 += __shfl_xor(sum0, 2);  sum1 += __shfl_xor(sum1, 2);
    sum0 += __shfl_xor(sum0, 4);  sum1 += __shfl_xor(sum1, 4);
    sum0 += __shfl_xor(sum0, 8);  sum1 += __shfl_xor(sum1, 8);

    if (lane == 0) {
        out[e0] = sum0;
        if (has1) out[e0 + 1] = sum1;
    }
}

extern "C" void kernel_launch(void* const* d_in, const int* in_sizes, int n_in,
                              void* d_out, int out_size, void* d_ws, size_t ws_size,
                              hipStream_t stream) {
    const float* user_h  = (const float*)d_in[0];
    const float* game_h  = (const float*)d_in[1];
    const int*   src_idx = (const int*)d_in[2];
    const int*   dst_idx = (const int*)d_in[3];
    float*       out     = (float*)d_out;

    int E       = in_sizes[2];
    int n_user  = in_sizes[0];   // N_USERS * D
    int n_game  = in_sizes[1];   // N_GAMES * D
    unsigned n_users = (unsigned)(n_user / DIM);
    unsigned n_games = (unsigned)(n_game / DIM);

    size_t rec_bytes = (size_t)NB * CAP * sizeof(unsigned);
    size_t res_bytes = (size_t)NB * CAP * sizeof(float);
    size_t pos_bytes = (size_t)E * sizeof(unsigned);
    size_t ws_full   = 8192 + rec_bytes + (size_t)n_user * 2 + (size_t)n_game * 2
                     + pos_bytes + res_bytes;

    // Guards: ws fits; CAP margin vs E; rel_src fits 11 bits; dst fits 16 bits.
    bool ok = (ws_size >= ws_full)
           && (E <= 1650000)
           && (n_users > 0) && (n_users <= (unsigned)NB * 2047u)
           && (n_games <= 65536u)
           && (n_user % (DIM) == 0) && (n_game % (DIM) == 0);

    if (!ok) {
        long long nblocks = ((long long)E + 31) / 32;
        edge_dot_kernel<<<(int)nblocks, 256, 0, stream>>>(
            user_h, game_h, src_idx, dst_idx, out, E);
        return;
    }

    char* p = (char*)d_ws;
    unsigned* cursors = (unsigned*)p;                 p += 8192;
    unsigned* records = (unsigned*)p;                 p += rec_bytes;
    uint4*    user_bf = (uint4*)p;                    p += (size_t)n_user * 2;
    uint4*    game_bf = (uint4*)p;                    p += (size_t)n_game * 2;
    unsigned* pos     = (unsigned*)p;                 p += pos_bytes;
    float*    res     = (float*)p;

    hipMemsetAsync(cursors, 0, 8192, stream);

    int nu8   = n_user / 8;
    int ng8   = n_game / 8;
    int nscat = (E + EPB_A - 1) / EPB_A;
    int nublk = (nu8 + 255) / 256;
    int ngblk = (ng8 + 255) / 256;

    prep_fused<<<nscat + nublk + ngblk, 256, 0, stream>>>(
        user_h, game_h, src_idx, dst_idx, E, n_users,
        cursors, records, pos, user_bf, game_bf,
        nscat, nublk, nu8, ng8);

    edge_dot_bucketed_bf16<<<NB * BPB, 256, 0, stream>>>(
        user_bf, game_bf, cursors, records, n_users, res);

    int n4 = E / 4;
    scatter_out<<<(n4 + 256) / 256, 256, 0, stream>>>(pos, res, out, E);
}

// Round 11
// 94.975 us; speedup vs baseline: 1.0131x; 1.0131x over previous
//
#include <hip/hip_runtime.h>

// Per-edge dot product: out[e] = dot(user_h[src[e]], game_h[dst[e]]), D=128.
//
// Prep (memsetAsync + 1 fused kernel):
//   [scatter blocks] bucket edges by SRC block into NB=64 buckets. Records are
//     4 B: rel_src:11 | dst:16. LDS-staged, flushed as coalesced runs.
//     pos[e] = global slot for the final out pass.
//   [convert blocks] BOTH tables f32 -> bf16 (row = 16 uint4).
// Main: bucket b on XCD slot b%8 (bid&7 round-robin), 8 buckets sequential
//   per XCD -> 400 KB bf16 user slice L2-resident; game bf16 random gather.
//   BPB=782 (measured fetch optimum: 163.8 MB; BPB=98 cost +15 MB by
//   de-localizing game-row L2 reuse). Dot uses float2 packed FMA
//   (v_pk_fma_f32). Results written SEQUENTIALLY to res.
// Final: out[e] = res[pos[e]] — pos has block-level locality.
// Fallback: direct f32 kernel if shape guards fail.

#define DIM 128
#define NB 64
#define CAP 28160        // per-bucket capacity (mean E/64, +many sigma)
#define BPB 782          // main-kernel chunks per bucket (1 iter/block)
#define EPB_A 4096
#define LCAP 128         // LDS staging slots per bucket per block

typedef float f32x2 __attribute__((ext_vector_type(2)));

__device__ inline unsigned bf16rn(float f) {
    unsigned x = __float_as_uint(f);
    return (x + 0x7FFFu + ((x >> 16) & 1u)) >> 16;
}

// Fused prep: blocks [0,nscat) scatter; [nscat,nscat+nublk) convert user;
// [nscat+nublk, nscat+nublk+ngblk) convert game.
__global__ void __launch_bounds__(256) prep_fused(
    const float* __restrict__ user_h, const float* __restrict__ game_h,
    const int* __restrict__ src_idx, const int* __restrict__ dst_idx, int E,
    unsigned n_users,
    unsigned* __restrict__ cursors, unsigned* __restrict__ records,
    unsigned* __restrict__ pos,
    uint4* __restrict__ user_bf, uint4* __restrict__ game_bf,
    int nscat, int nublk, int nu8, int ng8)
{
    __shared__ unsigned hist[NB];
    __shared__ unsigned base_s[NB];
    __shared__ unsigned lcur[NB];
    __shared__ unsigned stage[NB][LCAP];   // 32 KB
    int bid = blockIdx.x;
    int tid = threadIdx.x;

    if (bid >= nscat) {
        // ---- convert branch (straight element order) ----
        const float* in;
        uint4* outp;
        int i, n8;
        if (bid < nscat + nublk) {
            i = (bid - nscat) * 256 + tid;  n8 = nu8;  in = user_h;  outp = user_bf;
        } else {
            i = (bid - nscat - nublk) * 256 + tid;  n8 = ng8;  in = game_h;  outp = game_bf;
        }
        if (i < n8) {
            const float4* in4 = (const float4*)in;
            float4 a = in4[2 * i];
            float4 b = in4[2 * i + 1];
            uint4 o;
            o.x = bf16rn(a.x) | (bf16rn(a.y) << 16);
            o.y = bf16rn(a.z) | (bf16rn(a.w) << 16);
            o.z = bf16rn(b.x) | (bf16rn(b.y) << 16);
            o.w = bf16rn(b.z) | (bf16rn(b.w) << 16);
            outp[i] = o;
        }
        return;
    }

    // ---- scatter branch: bucket by SRC block, single idx read ----
    long long start = (long long)bid * EPB_A;
    unsigned ss[16], dd[16];

    #pragma unroll
    for (int k = 0; k < 16; ++k) {
        long long e = start + k * 256 + tid;
        bool v = (e < E);
        ss[k] = v ? (unsigned)src_idx[e] : 0xFFFFFFFFu;   // sentinel = invalid
        dd[k] = v ? (unsigned)dst_idx[e] : 0u;
    }

    if (tid < NB) hist[tid] = 0u;
    __syncthreads();

    #pragma unroll
    for (int k = 0; k < 16; ++k) {
        if (ss[k] != 0xFFFFFFFFu) {
            unsigned b = (ss[k] * (unsigned)NB) / n_users;
            atomicAdd(&hist[b], 1u);
        }
    }
    __syncthreads();

    if (tid < NB) {
        base_s[tid] = atomicAdd(&cursors[tid * 32], hist[tid]);  // prior count
        lcur[tid] = 0u;
    }
    __syncthreads();

    #pragma unroll
    for (int k = 0; k < 16; ++k) {
        if (ss[k] != 0xFFFFFFFFu) {
            unsigned s = ss[k], d = dd[k];
            unsigned b = (s * (unsigned)NB) / n_users;
            unsigned sbase = (b * n_users + (unsigned)NB - 1u) / (unsigned)NB;
            unsigned rec = (s - sbase) | (d << 11);    // rel_src:11 | dst:16
            unsigned r = atomicAdd(&lcur[b], 1u);
            unsigned slot = base_s[b] + r;
            long long e = start + k * 256 + tid;
            if (slot < (unsigned)CAP) {
                pos[e] = b * (unsigned)CAP + slot;
                if (r < (unsigned)LCAP) stage[b][r] = rec;          // common
                else records[(size_t)b * CAP + slot] = rec;          // rare
            } else {
                pos[e] = 0xFFFFFFFFu;                                // never
            }
        }
    }
    __syncthreads();

    // ---- coalesced flush: one wave per bucket, contiguous runs ----
    int wid  = tid >> 6;     // 0..3
    int lane = tid & 63;
    for (int b = wid; b < NB; b += 4) {
        unsigned n  = lcur[b]; if (n > (unsigned)LCAP) n = (unsigned)LCAP;
        unsigned bs = base_s[b];
        unsigned lim = (bs < (unsigned)CAP) ? ((unsigned)CAP - bs) : 0u;
        if (n > lim) n = lim;
        unsigned gbase = (unsigned)b * (unsigned)CAP + bs;
        for (unsigned i = lane; i < n; i += 64)
            records[gbase + i] = stage[b][i];
    }
}

// unpack one uint (2 bf16) into a float2 {lo, hi}
__device__ inline f32x2 bf2_unpack(unsigned u) {
    uint2 w;
    w.x = u << 16;
    w.y = u & 0xFFFF0000u;
    return *(f32x2*)&w;
}

// dot of 8 bf16 pairs via packed f32 FMA (v_pk_fma_f32)
__device__ inline float dot8_bf16(uint4 a, uint4 b) {
    f32x2 acc = bf2_unpack(a.x) * bf2_unpack(b.x);
    acc = bf2_unpack(a.y) * bf2_unpack(b.y) + acc;
    acc = bf2_unpack(a.z) * bf2_unpack(b.z) + acc;
    acc = bf2_unpack(a.w) * bf2_unpack(b.w) + acc;
    return acc.x + acc.y;
}

__global__ void __launch_bounds__(256) edge_dot_bucketed_bf16(
    const uint4* __restrict__ user_bf, const uint4* __restrict__ game_bf,
    const unsigned* __restrict__ cursors, const unsigned* __restrict__ records,
    unsigned n_users, float* __restrict__ res)
{
    int bid = blockIdx.x;
    int x = bid & 7;          // XCD slot (round-robin dispatch heuristic)
    int n = bid >> 3;
    int bq = n / BPB;         // which of this XCD's 8 buckets
    int chunk = n - bq * BPB;
    int b = x + 8 * bq;

    int count = (int)cursors[b * 32];
    if (count > CAP) count = CAP;
    const unsigned* __restrict__ rec = records + (size_t)b * CAP;
    float* __restrict__ rout = res + (size_t)b * CAP;
    unsigned sbase = ((unsigned)b * n_users + (unsigned)NB - 1u) / (unsigned)NB;

    int g    = threadIdx.x >> 4;   // 16-lane group (0..15)
    int lane = threadIdx.x & 15;

    for (int j0 = chunk * 32; j0 < count; j0 += BPB * 32) {
        int j = j0 + 2 * g;
        if (j >= count) continue;
        bool has1 = (j + 1 < count);

        uint2 rr = *(const uint2*)(rec + j);   // j even; CAP even so j+1 in range
        unsigned r0 = rr.x;
        unsigned r1 = has1 ? rr.y : rr.x;

        unsigned s0 = sbase + (r0 & 0x7FFu);
        unsigned d0 = r0 >> 11;
        unsigned s1 = sbase + (r1 & 0x7FFu);
        unsigned d1 = r1 >> 11;

        // lane owns elements [8*lane, 8*lane+8): 1 uint4 per row per table
        uint4 ua = user_bf[(size_t)s0 * 16 + lane];
        uint4 va = game_bf[(size_t)d0 * 16 + lane];
        uint4 ub = user_bf[(size_t)s1 * 16 + lane];
        uint4 vb = game_bf[(size_t)d1 * 16 + lane];

        float sum0 = dot8_bf16(ua, va);
        float sum1 = dot8_bf16(ub, vb);

        sum0 += __shfl_xor(sum0, 1);  sum1 += __shfl_xor(sum1, 1);
        sum0 += __shfl_xor(sum0, 2);  sum1 += __shfl_xor(sum1, 2);
        sum0 += __shfl_xor(sum0, 4);  sum1 += __shfl_xor(sum1, 4);
        sum0 += __shfl_xor(sum0, 8);  sum1 += __shfl_xor(sum1, 8);

        if (lane == 0) {
            if (has1) {
                *(float2*)(rout + j) = make_float2(sum0, sum1);  // j even
            } else {
                rout[j] = sum0;
            }
        }
    }
}

// Final: out[e] = res[pos[e]], vectorized x4; pos permutation is block-local.
__global__ void __launch_bounds__(256) scatter_out(
    const unsigned* __restrict__ pos, const float* __restrict__ res,
    float* __restrict__ out, int E)
{
    int i4 = blockIdx.x * blockDim.x + threadIdx.x;
    int n4 = E >> 2;
    if (i4 < n4) {
        uint4 p = ((const uint4*)pos)[i4];
        float4 o;
        o.x = (p.x != 0xFFFFFFFFu) ? res[p.x] : 0.0f;
        o.y = (p.y != 0xFFFFFFFFu) ? res[p.y] : 0.0f;
        o.z = (p.z != 0xFFFFFFFFu) ? res[p.z] : 0.0f;
        o.w = (p.w != 0xFFFFFFFFu) ? res[p.w] : 0.0f;
        ((float4*)out)[i4] = o;
    } else if (i4 == n4) {
        for (int e = n4 * 4; e < E; ++e) {
            unsigned p = pos[e];
            out[e] = (p != 0xFFFFFFFFu) ? res[p] : 0.0f;
        }
    }
}

// ---------------- direct fallback (all f32) ----------------
__global__ void __launch_bounds__(256) edge_dot_kernel(
    const float* __restrict__ user_h,
    const float* __restrict__ game_h,
    const int* __restrict__ src_idx,
    const int* __restrict__ dst_idx,
    float* __restrict__ out,
    int E)
{
    int tid  = blockIdx.x * blockDim.x + threadIdx.x;
    int g    = tid >> 4;
    int lane = tid & 15;
    long long e0 = (long long)g * 2;
    if (e0 >= E) return;
    bool has1 = (e0 + 1 < E);

    int s0 = src_idx[e0];
    int d0 = dst_idx[e0];
    int s1 = has1 ? src_idx[e0 + 1] : s0;
    int d1 = has1 ? dst_idx[e0 + 1] : d0;

    const float4* __restrict__ u0 = (const float4*)(user_h + (size_t)s0 * DIM);
    const float4* __restrict__ v0 = (const float4*)(game_h + (size_t)d0 * DIM);
    const float4* __restrict__ u1 = (const float4*)(user_h + (size_t)s1 * DIM);
    const float4* __restrict__ v1 = (const float4*)(game_h + (size_t)d1 * DIM);

    float4 ua0 = u0[lane];
    float4 ua1 = u0[lane + 16];
    float4 va0 = v0[lane];
    float4 va1 = v0[lane + 16];
    float4 ub0 = u1[lane];
    float4 ub1 = u1[lane + 16];
    float4 vb0 = v1[lane];
    float4 vb1 = v1[lane + 16];

    float sum0 = ua0.x * va0.x + ua0.y * va0.y + ua0.z * va0.z + ua0.w * va0.w
               + ua1.x * va1.x + ua1.y * va1.y + ua1.z * va1.z + ua1.w * va1.w;
    float sum1 = ub0.x * vb0.x + ub0.y * vb0.y + ub0.z * vb0.z + ub0.w * vb0.w
               + ub1.x * vb1.x + ub1.y * vb1.y + ub1.z * vb1.z + ub1.w * vb1.w;

    sum0 += __shfl_xor(sum0, 1);  sum1 += __shfl_xor(sum1, 1);
    sum0 += __shfl_xor(sum0, 2);  sum1 += __shfl_xor(sum1, 2);
    sum0 += __shfl_xor(sum0, 4);  sum1 += __shfl_xor(sum1, 4);
    sum0 += __shfl_xor(sum0, 8);  sum1 += __shfl_xor(sum1, 8);

    if (lane == 0) {
        out[e0] = sum0;
        if (has1) out[e0 + 1] = sum1;
    }
}

extern "C" void kernel_launch(void* const* d_in, const int* in_sizes, int n_in,
                              void* d_out, int out_size, void* d_ws, size_t ws_size,
                              hipStream_t stream) {
    const float* user_h  = (const float*)d_in[0];
    const float* game_h  = (const float*)d_in[1];
    const int*   src_idx = (const int*)d_in[2];
    const int*   dst_idx = (const int*)d_in[3];
    float*       out     = (float*)d_out;

    int E       = in_sizes[2];
    int n_user  = in_sizes[0];   // N_USERS * D
    int n_game  = in_sizes[1];   // N_GAMES * D
    unsigned n_users = (unsigned)(n_user / DIM);
    unsigned n_games = (unsigned)(n_game / DIM);

    size_t rec_bytes = (size_t)NB * CAP * sizeof(unsigned);
    size_t res_bytes = (size_t)NB * CAP * sizeof(float);
    size_t pos_bytes = (size_t)E * sizeof(unsigned);
    size_t ws_full   = 8192 + rec_bytes + (size_t)n_user * 2 + (size_t)n_game * 2
                     + pos_bytes + res_bytes;

    // Guards: ws fits; CAP margin vs E; rel_src fits 11 bits; dst fits 16 bits.
    bool ok = (ws_size >= ws_full)
           && (E <= 1650000)
           && (n_users > 0) && (n_users <= (unsigned)NB * 2047u)
           && (n_games <= 65536u)
           && (n_user % (DIM) == 0) && (n_game % (DIM) == 0);

    if (!ok) {
        long long nblocks = ((long long)E + 31) / 32;
        edge_dot_kernel<<<(int)nblocks, 256, 0, stream>>>(
            user_h, game_h, src_idx, dst_idx, out, E);
        return;
    }

    char* p = (char*)d_ws;
    unsigned* cursors = (unsigned*)p;                 p += 8192;
    unsigned* records = (unsigned*)p;                 p += rec_bytes;
    uint4*    user_bf = (uint4*)p;                    p += (size_t)n_user * 2;
    uint4*    game_bf = (uint4*)p;                    p += (size_t)n_game * 2;
    unsigned* pos     = (unsigned*)p;                 p += pos_bytes;
    float*    res     = (float*)p;

    hipMemsetAsync(cursors, 0, 8192, stream);

    int nu8   = n_user / 8;
    int ng8   = n_game / 8;
    int nscat = (E + EPB_A - 1) / EPB_A;
    int nublk = (nu8 + 255) / 256;
    int ngblk = (ng8 + 255) / 256;

    prep_fused<<<nscat + nublk + ngblk, 256, 0, stream>>>(
        user_h, game_h, src_idx, dst_idx, E, n_users,
        cursors, records, pos, user_bf, game_bf,
        nscat, nublk, nu8, ng8);

    edge_dot_bucketed_bf16<<<NB * BPB, 256, 0, stream>>>(
        user_bf, game_bf, cursors, records, n_users, res);

    int n4 = E / 4;
    scatter_out<<<(n4 + 256) / 256, 256, 0, stream>>>(pos, res, out, E);
}